// Round 1
// baseline (1238.382 us; speedup 1.0000x reference)
//
#include <hip/hip_runtime.h>

#define K_CLS 128
#define D_DIM 64
#define ACC_SZ (K_CLS * D_DIM + 2 * K_CLS)  // 8448 floats: [sums 8192 | cnt 128 | sumsq 128]
#define NPAIRS (K_CLS * (K_CLS - 1) / 2)    // 8128
#define K2_SLICES 16
#define K2_OCHUNKS ((ACC_SZ + 255) / 256)   // 33

// ---------------- K1: per-block segment partial sums via LDS atomics ----------------
__global__ __launch_bounds__(256) void k1_partials(
    const float* __restrict__ z, const int* __restrict__ labels,
    float* __restrict__ partials, float* __restrict__ totals, int nrows)
{
    __shared__ float s_acc[ACC_SZ];
    for (int o = threadIdx.x; o < ACC_SZ; o += 256) s_acc[o] = 0.f;
    __syncthreads();

    const int grp = threadIdx.x >> 4;   // 16 groups of 16 lanes per block
    const int l   = threadIdx.x & 15;   // lane within group; handles 4 floats of the row
    const float4* __restrict__ z4 = (const float4*)z;
    const int rstride = gridDim.x * 16;

    for (int row = blockIdx.x * 16 + grp; row < nrows; row += rstride) {
        float4 v = z4[row * 16 + l];
        int c = labels[row];
        float dot = v.x * v.x + v.y * v.y + v.z * v.z + v.w * v.w;
        // reduce ||z_row||^2 across the 16-lane group (masks stay inside the group)
        dot += __shfl_xor(dot, 1);
        dot += __shfl_xor(dot, 2);
        dot += __shfl_xor(dot, 4);
        dot += __shfl_xor(dot, 8);
        if ((unsigned)c < (unsigned)K_CLS) {
            float* dst = &s_acc[c * D_DIM + l * 4];
            unsafeAtomicAdd(dst + 0, v.x);
            unsafeAtomicAdd(dst + 1, v.y);
            unsafeAtomicAdd(dst + 2, v.z);
            unsafeAtomicAdd(dst + 3, v.w);
            if (l == 0) {
                unsafeAtomicAdd(&s_acc[K_CLS * D_DIM + c], 1.0f);
                unsafeAtomicAdd(&s_acc[K_CLS * D_DIM + K_CLS + c], dot);
            }
        }
    }
    __syncthreads();

    float* out = partials + (size_t)blockIdx.x * ACC_SZ;
    for (int o = threadIdx.x; o < ACC_SZ; o += 256) out[o] = s_acc[o];
    // block 0 zero-inits the totals accumulator for K2 (ws is poisoned each launch)
    if (blockIdx.x == 0) {
        for (int o = threadIdx.x; o < ACC_SZ; o += 256) totals[o] = 0.f;
    }
}

// ---------------- K2: slice-parallel reduction of partials -> totals ----------------
__global__ __launch_bounds__(256) void k2_reduce(
    const float* __restrict__ partials, float* __restrict__ totals, int G)
{
    int oc = blockIdx.x % K2_OCHUNKS;
    int s  = blockIdx.x / K2_OCHUNKS;
    int o = oc * 256 + threadIdx.x;
    if (o >= ACC_SZ) return;
    float acc = 0.f;
    for (int g = s; g < G; g += K2_SLICES)
        acc += partials[(size_t)g * ACC_SZ + o];
    unsafeAtomicAdd(&totals[o], acc);
}

// ---------------- K3: centers, var, intra + pairwise inter, final loss ----------------
__global__ __launch_bounds__(256) void k3_final(
    const float* __restrict__ totals, float* __restrict__ out)
{
    __shared__ float s_c[K_CLS * 68];   // centers, padded stride 68 (17 float4)
    __shared__ float s_cnt[K_CLS];
    __shared__ float s_nrm[K_CLS];
    __shared__ float s_var[K_CLS];
    __shared__ float s_red[4][5];
    const int tid = threadIdx.x;

    if (tid < K_CLS) s_cnt[tid] = totals[K_CLS * D_DIM + tid];
    __syncthreads();

    for (int idx = tid; idx < K_CLS * D_DIM; idx += 256) {
        int k = idx >> 6, d = idx & 63;
        s_c[k * 68 + d] = totals[idx] / fmaxf(s_cnt[k], 1.0f);
    }
    __syncthreads();

    if (tid < K_CLS) {
        float cs = 0.f;
        for (int d = 0; d < D_DIM; ++d) {
            float c = s_c[tid * 68 + d];
            cs = fmaf(c, c, cs);
        }
        s_nrm[tid] = cs;
        s_var[tid] = totals[K_CLS * D_DIM + K_CLS + tid] / fmaxf(s_cnt[tid], 1.0f) - cs;
    }
    __syncthreads();

    float intra = 0.f, nh2 = 0.f, nval = 0.f;
    if (tid < K_CLS) {
        float c = s_cnt[tid];
        if (c >= 0.5f) nval = 1.f;
        if (c >= 1.5f) { nh2 = 1.f; intra = s_var[tid]; }
    }

    float dsum = 0.f, npair = 0.f;
    const float4* __restrict__ c4 = (const float4*)s_c;  // row stride 17 float4
    for (int p = tid; p < NPAIRS; p += 256) {
        // decode p -> (i, j), i<j ; S(i) = i*(255-i)/2 pairs precede row i
        int i = (int)((255.0f - sqrtf((float)(65025 - 8 * p))) * 0.5f);
        if (i < 0) i = 0;
        if (i > 126) i = 126;
        while (i < 126 && (i + 1) * (255 - (i + 1)) / 2 <= p) ++i;
        while (i > 0 && i * (255 - i) / 2 > p) --i;
        int j = i + 1 + (p - i * (255 - i) / 2);

        bool ok = (s_cnt[i] >= 0.5f) && (s_cnt[j] >= 0.5f);
        const float4* ci = c4 + i * 17;
        const float4* cj = c4 + j * 17;
        float dot = 0.f;
        #pragma unroll
        for (int q = 0; q < 16; ++q) {
            float4 a = ci[q], b = cj[q];
            dot = fmaf(a.x, b.x, fmaf(a.y, b.y, fmaf(a.z, b.z, fmaf(a.w, b.w, dot))));
        }
        float sq = s_nrm[i] + s_nrm[j] - 2.f * dot;
        if (ok) {
            dsum += sqrtf(fmaxf(sq, 0.f));
            npair += 1.f;
        }
    }

    // block-wide reduce of {intra, nh2, nval, dsum, npair}
    float v0 = intra, v1 = nh2, v2 = nval, v3 = dsum, v4 = npair;
    for (int m = 1; m < 64; m <<= 1) {
        v0 += __shfl_xor(v0, m);
        v1 += __shfl_xor(v1, m);
        v2 += __shfl_xor(v2, m);
        v3 += __shfl_xor(v3, m);
        v4 += __shfl_xor(v4, m);
    }
    const int wv = tid >> 6;
    if ((tid & 63) == 0) {
        s_red[wv][0] = v0; s_red[wv][1] = v1; s_red[wv][2] = v2;
        s_red[wv][3] = v3; s_red[wv][4] = v4;
    }
    __syncthreads();
    if (tid == 0) {
        float t0 = 0.f, t1 = 0.f, t2 = 0.f, t3 = 0.f, t4 = 0.f;
        for (int w = 0; w < 4; ++w) {
            t0 += s_red[w][0]; t1 += s_red[w][1]; t2 += s_red[w][2];
            t3 += s_red[w][3]; t4 += s_red[w][4];
        }
        float intra_loss = (t1 > 0.5f) ? (t0 / t1) : 0.f;
        float inter_loss = (t4 > 0.5f) ? (-t3 / t4) : 0.f;
        float loss = intra_loss + 0.5f * inter_loss;
        out[0] = (t2 >= 1.5f) ? loss : 0.f;
    }
}

// ---------------- host ----------------
extern "C" void kernel_launch(void* const* d_in, const int* in_sizes, int n_in,
                              void* d_out, int out_size, void* d_ws, size_t ws_size,
                              hipStream_t stream) {
    const float* z      = (const float*)d_in[0];
    const int*   labels = (const int*)d_in[1];
    float*       out    = (float*)d_out;
    const int N = in_sizes[1];

    int G = 1024;
    size_t need = ((size_t)G + 1) * ACC_SZ * sizeof(float);
    if (need > ws_size) {
        long long fit = (long long)(ws_size / (sizeof(float) * (size_t)ACC_SZ)) - 1;
        G = (fit < 1) ? 1 : (fit > 1024 ? 1024 : (int)fit);
    }
    float* partials = (float*)d_ws;
    float* totals   = partials + (size_t)G * ACC_SZ;

    hipLaunchKernelGGL(k1_partials, dim3(G), dim3(256), 0, stream, z, labels, partials, totals, N);
    hipLaunchKernelGGL(k2_reduce, dim3(K2_OCHUNKS * K2_SLICES), dim3(256), 0, stream, partials, totals, G);
    hipLaunchKernelGGL(k3_final, dim3(1), dim3(256), 0, stream, totals, out);
}